// Round 1
// baseline (1239.572 us; speedup 1.0000x reference)
//
#include <hip/hip_runtime.h>

// Problem constants (B=4, S=2048, D=2048, F=8192, G=8, K=1)
#define T_TOK 8192   // B*S tokens
#define D_DIM 2048
#define F_DIM 8192
#define G_NUM 8
#define GF    1024   // features per group = F/G

// ---------------------------------------------------------------------------
// ws layout:
//   [0, 32)        : int cnt[8]
//   [256, 256+256K): int bucket[8][8192]
//   [512K, +32MB)  : float H[8192][1024]  (post-ReLU hidden, per token)
// ---------------------------------------------------------------------------

__global__ void zero_cnt_kernel(int* __restrict__ cnt) {
    if (threadIdx.x < G_NUM) cnt[threadIdx.x] = 0;
}

// One wave (64 lanes) per token: 8 dot products of length 2048, fp64 accum
// (argmax must match numpy ref; near-ties are the only correctness hazard).
__global__ __launch_bounds__(256)
void gate_kernel(const float* __restrict__ x, const float* __restrict__ Wm,
                 const float* __restrict__ bm, int* __restrict__ cnt,
                 int* __restrict__ bucket) {
    const int wave  = threadIdx.x >> 6;
    const int lane  = threadIdx.x & 63;
    const int token = blockIdx.x * 4 + wave;
    const float* xr = x + (size_t)token * D_DIM;

    double acc[G_NUM];
#pragma unroll
    for (int g = 0; g < G_NUM; ++g) acc[g] = 0.0;

    for (int d = lane; d < D_DIM; d += 64) {
        float xv = xr[d];
#pragma unroll
        for (int g = 0; g < G_NUM; ++g)
            acc[g] += (double)xv * (double)Wm[g * D_DIM + d];
    }

#pragma unroll
    for (int g = 0; g < G_NUM; ++g) {
#pragma unroll
        for (int m = 32; m >= 1; m >>= 1)
            acc[g] += __shfl_xor(acc[g], m);
    }

    if (lane == 0) {
        double best = acc[0] + (double)bm[0];
        int bg = 0;
#pragma unroll
        for (int g = 1; g < G_NUM; ++g) {
            double v = acc[g] + (double)bm[g];
            if (v > best) { best = v; bg = g; }  // strict > keeps lowest index on ties (top_k semantics)
        }
        int pos = atomicAdd(&cnt[bg], 1);
        bucket[bg * T_TOK + pos] = token;
    }
}

// ---------------------------------------------------------------------------
// GEMM1: H[tok, f] = relu( x[tok,:] . W1[g*GF+f, :] + b1[g*GF+f] )
// Gather rows of x via bucket list. Tile 64 tokens x 64 features, K-chunk 16.
// 256 threads, 4x4 register blocking per thread.
// LDS stored K-major (As[k][row], pad 68) so compute reads are ds_read_b128.
// ---------------------------------------------------------------------------
__global__ __launch_bounds__(256)
void gemm1_kernel(const float* __restrict__ x, const float* __restrict__ W1,
                  const float* __restrict__ b1, const int* __restrict__ cnt,
                  const int* __restrict__ bucket, float* __restrict__ H) {
    const int g  = blockIdx.z;
    const int n  = cnt[g];
    const int t0 = blockIdx.y * 64;
    if (t0 >= n) return;
    const int f0  = blockIdx.x * 64;   // feature offset within group [0, GF)
    const int tid = threadIdx.x;

    __shared__ int   toks[64];
    __shared__ float As[16][68];
    __shared__ float Bs[16][68];

    if (tid < 64) {
        int r = t0 + tid;
        toks[tid] = (r < n) ? bucket[g * T_TOK + r] : 0;  // clamp invalid rows to token 0
    }
    __syncthreads();

    const int tx = tid & 15, ty = tid >> 4;
    const int lr = tid >> 2;          // loader row 0..63
    const int lk = (tid & 3) << 2;    // loader k offset 0,4,8,12

    const float* Ap = x  + (size_t)toks[lr] * D_DIM + lk;
    const float* Bp = W1 + (size_t)(g * GF + f0 + lr) * D_DIM + lk;

    float acc[4][4] = {};

    for (int k0 = 0; k0 < D_DIM; k0 += 16) {
        float4 av = *(const float4*)(Ap + k0);
        float4 bv = *(const float4*)(Bp + k0);
        As[lk + 0][lr] = av.x; As[lk + 1][lr] = av.y;
        As[lk + 2][lr] = av.z; As[lk + 3][lr] = av.w;
        Bs[lk + 0][lr] = bv.x; Bs[lk + 1][lr] = bv.y;
        Bs[lk + 2][lr] = bv.z; Bs[lk + 3][lr] = bv.w;
        __syncthreads();
#pragma unroll
        for (int k = 0; k < 16; ++k) {
            float4 a4 = *(const float4*)&As[k][ty << 2];
            float4 b4 = *(const float4*)&Bs[k][tx << 2];
            float a_[4] = {a4.x, a4.y, a4.z, a4.w};
            float b_[4] = {b4.x, b4.y, b4.z, b4.w};
#pragma unroll
            for (int i = 0; i < 4; ++i)
#pragma unroll
                for (int j = 0; j < 4; ++j)
                    acc[i][j] += a_[i] * b_[j];
        }
        __syncthreads();
    }

    const int fl = f0 + (tx << 2);                       // local feature of col 0
    float4 bb = *(const float4*)&b1[g * GF + fl];
#pragma unroll
    for (int i = 0; i < 4; ++i) {
        int r = (ty << 2) + i;
        if (t0 + r < n) {
            float4 o;
            o.x = fmaxf(acc[i][0] + bb.x, 0.f);
            o.y = fmaxf(acc[i][1] + bb.y, 0.f);
            o.z = fmaxf(acc[i][2] + bb.z, 0.f);
            o.w = fmaxf(acc[i][3] + bb.w, 0.f);
            *(float4*)&H[(size_t)toks[r] * GF + fl] = o;
        }
    }
}

// ---------------------------------------------------------------------------
// GEMM2: out[tok, d] = b2[d] + H[tok,:] . W2[d, g*GF : (g+1)*GF]
// Same tile structure; K = GF = 1024.
// ---------------------------------------------------------------------------
__global__ __launch_bounds__(256)
void gemm2_kernel(const float* __restrict__ H, const float* __restrict__ W2,
                  const float* __restrict__ b2, const int* __restrict__ cnt,
                  const int* __restrict__ bucket, float* __restrict__ out) {
    const int g  = blockIdx.z;
    const int n  = cnt[g];
    const int t0 = blockIdx.y * 64;
    if (t0 >= n) return;
    const int d0  = blockIdx.x * 64;
    const int tid = threadIdx.x;

    __shared__ int   toks[64];
    __shared__ float As[16][68];
    __shared__ float Bs[16][68];

    if (tid < 64) {
        int r = t0 + tid;
        toks[tid] = (r < n) ? bucket[g * T_TOK + r] : 0;
    }
    __syncthreads();

    const int tx = tid & 15, ty = tid >> 4;
    const int lr = tid >> 2;
    const int lk = (tid & 3) << 2;

    const float* Ap = H  + (size_t)toks[lr] * GF + lk;
    const float* Bp = W2 + (size_t)(d0 + lr) * F_DIM + g * GF + lk;

    float acc[4][4] = {};

    for (int k0 = 0; k0 < GF; k0 += 16) {
        float4 av = *(const float4*)(Ap + k0);
        float4 bv = *(const float4*)(Bp + k0);
        As[lk + 0][lr] = av.x; As[lk + 1][lr] = av.y;
        As[lk + 2][lr] = av.z; As[lk + 3][lr] = av.w;
        Bs[lk + 0][lr] = bv.x; Bs[lk + 1][lr] = bv.y;
        Bs[lk + 2][lr] = bv.z; Bs[lk + 3][lr] = bv.w;
        __syncthreads();
#pragma unroll
        for (int k = 0; k < 16; ++k) {
            float4 a4 = *(const float4*)&As[k][ty << 2];
            float4 b4 = *(const float4*)&Bs[k][tx << 2];
            float a_[4] = {a4.x, a4.y, a4.z, a4.w};
            float b_[4] = {b4.x, b4.y, b4.z, b4.w};
#pragma unroll
            for (int i = 0; i < 4; ++i)
#pragma unroll
                for (int j = 0; j < 4; ++j)
                    acc[i][j] += a_[i] * b_[j];
        }
        __syncthreads();
    }

    const int dl = d0 + (tx << 2);
    float4 bb = *(const float4*)&b2[dl];
#pragma unroll
    for (int i = 0; i < 4; ++i) {
        int r = (ty << 2) + i;
        if (t0 + r < n) {
            float4 o;
            o.x = acc[i][0] + bb.x;
            o.y = acc[i][1] + bb.y;
            o.z = acc[i][2] + bb.z;
            o.w = acc[i][3] + bb.w;
            *(float4*)&out[(size_t)toks[r] * D_DIM + dl] = o;
        }
    }
}

extern "C" void kernel_launch(void* const* d_in, const int* in_sizes, int n_in,
                              void* d_out, int out_size, void* d_ws, size_t ws_size,
                              hipStream_t stream) {
    const float* x  = (const float*)d_in[0];
    const float* W1 = (const float*)d_in[1];
    const float* b1 = (const float*)d_in[2];
    const float* Wm = (const float*)d_in[3];
    const float* bm = (const float*)d_in[4];
    const float* W2 = (const float*)d_in[5];
    const float* b2 = (const float*)d_in[6];
    float* out = (float*)d_out;

    int*   cnt    = (int*)d_ws;
    int*   bucket = (int*)((char*)d_ws + 256);
    float* H      = (float*)((char*)d_ws + (1 << 19));  // 512 KB offset; needs 512K + 32MB of ws

    zero_cnt_kernel<<<1, 64, 0, stream>>>(cnt);
    gate_kernel<<<T_TOK / 4, 256, 0, stream>>>(x, Wm, bm, cnt, bucket);
    gemm1_kernel<<<dim3(GF / 64, T_TOK / 64, G_NUM), 256, 0, stream>>>(x, W1, b1, cnt, bucket, H);
    gemm2_kernel<<<dim3(D_DIM / 64, T_TOK / 64, G_NUM), 256, 0, stream>>>(H, W2, b2, cnt, bucket, out);
}

// Round 3
// 468.210 us; speedup vs baseline: 2.6475x; 2.6475x over previous
//
#include <hip/hip_runtime.h>
#include <hip/hip_bf16.h>

// Problem constants (B=4, S=2048, D=2048, F=8192, G=8, K=1)
#define T_TOK 8192   // B*S tokens
#define D_DIM 2048
#define F_DIM 8192
#define G_NUM 8
#define GF    1024   // features per group = F/G

typedef __attribute__((ext_vector_type(8))) short bf16x8;  // 8 bf16 (4 VGPRs)
typedef __attribute__((ext_vector_type(4))) float f32x4;

// async global->LDS, 16B per lane. HW semantics: LDS dest = wave-uniform base
// (first lane's value) + lane*16; global address is per-lane (gather is fine).
__device__ __forceinline__ void async_load16(const void* g, void* l) {
    __builtin_amdgcn_global_load_lds(
        (const __attribute__((address_space(1))) unsigned int*)g,
        (__attribute__((address_space(3))) unsigned int*)l, 16, 0, 0);
}

__device__ __forceinline__ unsigned short f2bf(float f) {
    unsigned int u = __float_as_uint(f);
    unsigned int r = (u + 0x7fffu + ((u >> 16) & 1u)) >> 16;  // RNE
    return (unsigned short)r;
}

__device__ __forceinline__ uint2 pack4(float4 v) {
    union { __hip_bfloat162 b; unsigned u; } c0, c1;
    c0.b = __float22bfloat162_rn({v.x, v.y});
    c1.b = __float22bfloat162_rn({v.z, v.w});
    uint2 r; r.x = c0.u; r.y = c1.u; return r;
}

// ---------------------------------------------------------------------------
// ws layout (FAST, needs 117,964,800 B):
//   [0,32) cnt | [1K,257K) bucket | [512K,+16M) Hb | +32M xb | +32M W1b | +32M W2b
// ws layout (SAFE, needs 17,301,504 B): cnt | bucket | Hb only
// ---------------------------------------------------------------------------

__global__ void zero_cnt_kernel(int* __restrict__ cnt) {
    if (threadIdx.x < G_NUM) cnt[threadIdx.x] = 0;
}

// fp32 -> bf16, 8 elems/thread
__global__ __launch_bounds__(256)
void convert_kernel(const float* __restrict__ src, unsigned short* __restrict__ dst, int n) {
    int i = (blockIdx.x * 256 + threadIdx.x) * 8;
    if (i >= n) return;
    float4 a = *(const float4*)(src + i);
    float4 b = *(const float4*)(src + i + 4);
    uint2 p0 = pack4(a), p1 = pack4(b);
    uint4 o; o.x = p0.x; o.y = p0.y; o.z = p1.x; o.w = p1.y;
    *(uint4*)(dst + i) = o;
}

// One wave per token: argmax_g(x . Wm[g] + bm[g]), fp64 accum (validated vs np ref).
__global__ __launch_bounds__(256)
void gate_kernel(const float* __restrict__ x, const float* __restrict__ Wm,
                 const float* __restrict__ bm, int* __restrict__ cnt,
                 int* __restrict__ bucket) {
    const int wave  = threadIdx.x >> 6;
    const int lane  = threadIdx.x & 63;
    const int token = blockIdx.x * 4 + wave;
    const float* xr = x + (size_t)token * D_DIM;

    double acc[G_NUM];
#pragma unroll
    for (int g = 0; g < G_NUM; ++g) acc[g] = 0.0;

    for (int d = lane; d < D_DIM; d += 64) {
        float xv = xr[d];
#pragma unroll
        for (int g = 0; g < G_NUM; ++g)
            acc[g] += (double)xv * (double)Wm[g * D_DIM + d];
    }

#pragma unroll
    for (int g = 0; g < G_NUM; ++g) {
#pragma unroll
        for (int m = 32; m >= 1; m >>= 1)
            acc[g] += __shfl_xor(acc[g], m);
    }

    if (lane == 0) {
        double best = acc[0] + (double)bm[0];
        int bg = 0;
#pragma unroll
        for (int g = 1; g < G_NUM; ++g) {
            double v = acc[g] + (double)bm[g];
            if (v > best) { best = v; bg = g; }  // strict > == top_k lowest-index tie rule
        }
        int pos = atomicAdd(&cnt[bg], 1);
        bucket[bg * T_TOK + pos] = token;
    }
}

// ---------------------------------------------------------------------------
// bf16 MFMA GEMM (m97 structure) with row gather via bucket.
// 128x128 tile, BK=32, 256 threads = 4 waves, each wave 64x64 via 4x4 MFMAs.
// A_BF16/B_BF16: operand is pre-converted bf16 (async global_load_lds staging)
// vs fp32 global (register-load + in-register RNE pack + ds_write_b128).
// IS_G1: A rows gathered from x-like [*, KDIM]; B rows = W1[g*GF+nx0+..], out bf16 relu(.+b1)
// else : A rows gathered from Hb [*, GF]; B rows = W2[nx0+..] col-offset g*GF, out f32 .+b2
// ---------------------------------------------------------------------------
template <int KDIM, bool IS_G1, bool A_BF16, bool B_BF16>
__global__ __launch_bounds__(256)
void mfma_gemm(const void* __restrict__ Aop, const void* __restrict__ Bop,
               const float* __restrict__ bias,
               const int* __restrict__ cnt, const int* __restrict__ bucket,
               unsigned short* __restrict__ outH, float* __restrict__ outF) {
    const int g  = blockIdx.z;
    const int n  = cnt[g];
    const int t0 = blockIdx.y * 128;
    if (t0 >= n) return;
    const int nx0 = blockIdx.x * 128;
    const int tid  = threadIdx.x;
    const int lane = tid & 63;
    const int wv   = tid >> 6;

    __shared__ int toks[128];
    __shared__ __align__(16) unsigned short As[128 * 32];  // [row][k], 64B rows
    __shared__ __align__(16) unsigned short Bs[128 * 32];

    if (tid < 128) {
        int r = t0 + tid;
        if (r >= n) r = n - 1;       // clamp: duplicate last valid token, masked on store
        toks[tid] = bucket[g * T_TOK + r];
    }
    __syncthreads();

    const size_t bstride = IS_G1 ? (size_t)KDIM : (size_t)F_DIM;
    const size_t brow0   = IS_G1 ? (size_t)(g * GF + nx0) : (size_t)nx0;
    const size_t bcol    = IS_G1 ? 0 : (size_t)(g * GF);

    // --- bf16 async staging mapping: chunk c = tid, row c>>2, seg c&3 ---
    const int lrow = tid >> 2;
    const int lseg = tid & 3;
    const unsigned short* aP0 = nullptr; const unsigned short* aP1 = nullptr;
    const unsigned short* bP0 = nullptr; const unsigned short* bP1 = nullptr;
    char *ldsA0 = nullptr, *ldsA1 = nullptr, *ldsB0 = nullptr, *ldsB1 = nullptr;
    if (A_BF16) {
        const unsigned short* Ab = (const unsigned short*)Aop;
        aP0 = Ab + (size_t)toks[lrow] * KDIM + lseg * 8;
        aP1 = Ab + (size_t)toks[64 + lrow] * KDIM + lseg * 8;
        ldsA0 = (char*)As + tid * 16;
        ldsA1 = (char*)As + 4096 + tid * 16;
    }
    if (B_BF16) {
        const unsigned short* Bb = (const unsigned short*)Bop;
        bP0 = Bb + (brow0 + lrow) * bstride + bcol + lseg * 8;
        bP1 = Bb + (brow0 + 64 + lrow) * bstride + bcol + lseg * 8;
        ldsB0 = (char*)Bs + tid * 16;
        ldsB1 = (char*)Bs + 4096 + tid * 16;
    }

    // --- fp32 register staging mapping: row tid>>1, 16 k-elems at (tid&1)*16 ---
    const int frw = tid >> 1;
    const int fsg = (tid & 1) * 16;
    const float* aF = nullptr; const float* bF = nullptr;
    char *ldsAf = nullptr, *ldsBf = nullptr;
    if (!A_BF16) {
        aF = (const float*)Aop + (size_t)toks[frw] * KDIM + fsg;
        ldsAf = (char*)As + frw * 64 + (tid & 1) * 32;
    }
    if (!B_BF16) {
        bF = (const float*)Bop + (brow0 + frw) * bstride + bcol + fsg;
        ldsBf = (char*)Bs + frw * 64 + (tid & 1) * 32;
    }

    f32x4 acc[4][4];
#pragma unroll
    for (int mi = 0; mi < 4; ++mi)
#pragma unroll
        for (int ni = 0; ni < 4; ++ni)
            acc[mi][ni] = (f32x4){0.f, 0.f, 0.f, 0.f};

    const int wr   = (wv >> 1) * 64;   // wave row offset in 128-tile
    const int wc   = (wv & 1) * 64;    // wave col offset
    const int frow = lane & 15;
    const int kh   = lane >> 4;

    for (int k0 = 0; k0 < KDIM; k0 += 32) {
        __syncthreads();               // prev iter's LDS reads done
        if (A_BF16) { async_load16(aP0 + k0, ldsA0); async_load16(aP1 + k0, ldsA1); }
        if (B_BF16) { async_load16(bP0 + k0, ldsB0); async_load16(bP1 + k0, ldsB1); }
        if (!A_BF16) {
            float4 v0 = *(const float4*)(aF + k0);
            float4 v1 = *(const float4*)(aF + k0 + 4);
            float4 v2 = *(const float4*)(aF + k0 + 8);
            float4 v3 = *(const float4*)(aF + k0 + 12);
            uint2 p0 = pack4(v0), p1 = pack4(v1), p2 = pack4(v2), p3 = pack4(v3);
            uint4 w0; w0.x = p0.x; w0.y = p0.y; w0.z = p1.x; w0.w = p1.y;
            uint4 w1; w1.x = p2.x; w1.y = p2.y; w1.z = p3.x; w1.w = p3.y;
            *(uint4*)ldsAf = w0; *(uint4*)(ldsAf + 16) = w1;
        }
        if (!B_BF16) {
            float4 v0 = *(const float4*)(bF + k0);
            float4 v1 = *(const float4*)(bF + k0 + 4);
            float4 v2 = *(const float4*)(bF + k0 + 8);
            float4 v3 = *(const float4*)(bF + k0 + 12);
            uint2 p0 = pack4(v0), p1 = pack4(v1), p2 = pack4(v2), p3 = pack4(v3);
            uint4 w0; w0.x = p0.x; w0.y = p0.y; w0.z = p1.x; w0.w = p1.y;
            uint4 w1; w1.x = p2.x; w1.y = p2.y; w1.z = p3.x; w1.w = p3.y;
            *(uint4*)ldsBf = w0; *(uint4*)(ldsBf + 16) = w1;
        }
        __syncthreads();               // staging visible (vmcnt + lgkmcnt drained)
        bf16x8 af[4], bfr[4];
#pragma unroll
        for (int mi = 0; mi < 4; ++mi)
            af[mi] = *(const bf16x8*)((const char*)As + (size_t)(wr + mi * 16 + frow) * 64 + kh * 16);
#pragma unroll
        for (int ni = 0; ni < 4; ++ni)
            bfr[ni] = *(const bf16x8*)((const char*)Bs + (size_t)(wc + ni * 16 + frow) * 64 + kh * 16);
#pragma unroll
        for (int mi = 0; mi < 4; ++mi)
#pragma unroll
            for (int ni = 0; ni < 4; ++ni)
                acc[mi][ni] = __builtin_amdgcn_mfma_f32_16x16x32_bf16(
                    af[mi], bfr[ni], acc[mi][ni], 0, 0, 0);
    }

    // epilogue: C elem (row = mi*16 + kh*4 + v, col = ni*16 + frow)  [m89 mapping]
    const float* bptr = bias + (IS_G1 ? (g * GF + nx0) : nx0);
    float bv[4];
#pragma unroll
    for (int ni = 0; ni < 4; ++ni) bv[ni] = bptr[wc + ni * 16 + frow];

#pragma unroll
    for (int mi = 0; mi < 4; ++mi) {
#pragma unroll
        for (int v = 0; v < 4; ++v) {
            int r = wr + mi * 16 + kh * 4 + v;
            if (t0 + r < n) {
                int tok = toks[r];
                if (IS_G1) {
                    unsigned short* dst = outH + (size_t)tok * GF + nx0 + wc + frow;
#pragma unroll
                    for (int ni = 0; ni < 4; ++ni) {
                        float o = fmaxf(acc[mi][ni][v] + bv[ni], 0.f);
                        dst[ni * 16] = f2bf(o);
                    }
                } else {
                    float* dst = outF + (size_t)tok * D_DIM + nx0 + wc + frow;
#pragma unroll
                    for (int ni = 0; ni < 4; ++ni)
                        dst[ni * 16] = acc[mi][ni][v] + bv[ni];
                }
            }
        }
    }
}

extern "C" void kernel_launch(void* const* d_in, const int* in_sizes, int n_in,
                              void* d_out, int out_size, void* d_ws, size_t ws_size,
                              hipStream_t stream) {
    const float* x  = (const float*)d_in[0];
    const float* W1 = (const float*)d_in[1];
    const float* b1 = (const float*)d_in[2];
    const float* Wm = (const float*)d_in[3];
    const float* bm = (const float*)d_in[4];
    const float* W2 = (const float*)d_in[5];
    const float* b2 = (const float*)d_in[6];
    float* out = (float*)d_out;

    int* cnt    = (int*)d_ws;
    int* bucket = (int*)((char*)d_ws + 1024);
    unsigned short* Hb  = (unsigned short*)((char*)d_ws + (1 << 19));
    unsigned short* xb  = Hb  + (size_t)T_TOK * GF;
    unsigned short* W1b = xb  + (size_t)T_TOK * D_DIM;
    unsigned short* W2b = W1b + (size_t)F_DIM * D_DIM;

    // FAST needs 512K + 16M + 3*32M = 117,964,800 B of ws; SAFE needs 17,301,504 B.
    const bool fast = ws_size >= 117964800ull;
    const int NCVT = T_TOK * D_DIM;  // == F*D == D*F == 16777216

    zero_cnt_kernel<<<1, 64, 0, stream>>>(cnt);
    gate_kernel<<<T_TOK / 4, 256, 0, stream>>>(x, Wm, bm, cnt, bucket);

    if (fast) {
        convert_kernel<<<NCVT / (256 * 8), 256, 0, stream>>>(x, xb, NCVT);
        convert_kernel<<<NCVT / (256 * 8), 256, 0, stream>>>(W1, W1b, NCVT);
        convert_kernel<<<NCVT / (256 * 8), 256, 0, stream>>>(W2, W2b, NCVT);
        mfma_gemm<D_DIM, true, true, true><<<dim3(GF / 128, T_TOK / 128, G_NUM), 256, 0, stream>>>(
            xb, W1b, b1, cnt, bucket, Hb, nullptr);
        mfma_gemm<GF, false, true, true><<<dim3(D_DIM / 128, T_TOK / 128, G_NUM), 256, 0, stream>>>(
            Hb, W2b, b2, cnt, bucket, nullptr, out);
    } else {
        mfma_gemm<D_DIM, true, false, false><<<dim3(GF / 128, T_TOK / 128, G_NUM), 256, 0, stream>>>(
            x, W1, b1, cnt, bucket, Hb, nullptr);
        mfma_gemm<GF, false, true, false><<<dim3(D_DIM / 128, T_TOK / 128, G_NUM), 256, 0, stream>>>(
            Hb, W2, b2, cnt, bucket, nullptr, out);
    }
}

// Round 4
// 406.155 us; speedup vs baseline: 3.0520x; 1.1528x over previous
//
#include <hip/hip_runtime.h>
#include <hip/hip_bf16.h>

// Problem constants (B=4, S=2048, D=2048, F=8192, G=8, K=1)
#define T_TOK 8192   // B*S tokens
#define D_DIM 2048
#define F_DIM 8192
#define G_NUM 8
#define GF    1024   // features per group = F/G

typedef __attribute__((ext_vector_type(8))) short bf16x8;  // 8 bf16 (4 VGPRs)
typedef __attribute__((ext_vector_type(4))) float f32x4;

// async global->LDS, 16B per lane. HW semantics: LDS dest = wave-uniform base
// (first lane's value) + lane*16; global address is per-lane (gather is fine).
__device__ __forceinline__ void async_load16(const void* g, void* l) {
    __builtin_amdgcn_global_load_lds(
        (const __attribute__((address_space(1))) unsigned int*)g,
        (__attribute__((address_space(3))) unsigned int*)l, 16, 0, 0);
}

__device__ __forceinline__ unsigned short f2bf(float f) {
    unsigned int u = __float_as_uint(f);
    unsigned int r = (u + 0x7fffu + ((u >> 16) & 1u)) >> 16;  // RNE
    return (unsigned short)r;
}

__device__ __forceinline__ uint2 pack4(float4 v) {
    union { __hip_bfloat162 b; unsigned u; } c0, c1;
    c0.b = __float22bfloat162_rn({v.x, v.y});
    c1.b = __float22bfloat162_rn({v.z, v.w});
    uint2 r; r.x = c0.u; r.y = c1.u; return r;
}

// ---------------------------------------------------------------------------
// ws layout (offsets in MiB unless noted):
//   [0,32B) cnt | [1KiB,257KiB) bucket[8][8192]
//   part (fp64, 2 MiB) @ 0.5 MiB  -- ALIASES Hb; consumed by combine before
//                                    gemm1 writes Hb (stream-ordered, safe)
//   Hb  @ 0.5  (16 MiB bf16 H)
//   xb  @ 16.5 (32 MiB bf16 x)          [FAST+MID]
//   W1b @ 48.5 (32 MiB), W2b @ 80.5 (32 MiB)   [FAST only]
// FAST needs 112.5 MiB; MID needs 48.5 MiB; SAFE needs 16.5 MiB.
// ---------------------------------------------------------------------------

__global__ void zero_cnt_kernel(int* __restrict__ cnt) {
    if (threadIdx.x < G_NUM) cnt[threadIdx.x] = 0;
}

// fp32 -> bf16, 8 elems/thread
__global__ __launch_bounds__(256)
void convert_kernel(const float* __restrict__ src, unsigned short* __restrict__ dst, int n) {
    int i = (blockIdx.x * 256 + threadIdx.x) * 8;
    if (i >= n) return;
    float4 a = *(const float4*)(src + i);
    float4 b = *(const float4*)(src + i + 4);
    uint2 p0 = pack4(a), p1 = pack4(b);
    uint4 o; o.x = p0.x; o.y = p0.y; o.z = p1.x; o.w = p1.y;
    *(uint4*)(dst + i) = o;
}

// ---------------------------------------------------------------------------
// Gate phase 1: lane = token. Block = 1 wave (64 thr). Grid = (4 quarters, 128
// token-tiles). Each block: stage Wm quarter [8][512] to LDS once; stream x in
// 64-d chunks through LDS (coalesced load -> row-layout read), 8 fp64 accs per
// lane (no reductions), register-prefetch next chunk under compute. Fused
// fp32->bf16 conversion of x written to xb (WRITE_XB).
// fp64 partials to `part`; combine kernel does sum+bias+argmax+bucket.
// ---------------------------------------------------------------------------
template <bool WRITE_XB>
__global__ __launch_bounds__(64)
void gate_partial_kernel(const float* __restrict__ x, const float* __restrict__ Wm,
                         unsigned short* __restrict__ xb, double* __restrict__ part) {
    const int q     = blockIdx.x;      // k-quarter
    const int t     = blockIdx.y;      // token tile
    const int lane  = threadIdx.x;
    const int tok0  = t * 64;
    const int kbase = q * 512;

    __shared__ float wmS[8][512];      // 16 KiB, wave-uniform reads (broadcast)
    __shared__ float xs[64][68];       // 17.4 KiB; stride 68 floats = 17*16B (b128-aligned)

    // preload Wm quarter: 4096 floats, 16 float4 per lane
    for (int i = lane * 4; i < 8 * 512; i += 64 * 4) {
        int g = i >> 9, d = i & 511;
        *(float4*)&wmS[g][d] = *(const float4*)(Wm + (size_t)g * D_DIM + kbase + d);
    }

    double acc[8] = {0, 0, 0, 0, 0, 0, 0, 0};

    const int srow = lane >> 2;        // 0..15
    const int scol = (lane & 3) * 4;   // 0,4,8,12 (floats)

    float4 v[16];
    // chunk = 64 tokens x 64 d. 16 float4/lane: row = it*16+srow, col = ci*16+scol.
    // 4-lane groups cover 64B contiguous per row (coalesced 64B segments).
#define LOAD_CHUNK(dbase_)                                                        \
    _Pragma("unroll") for (int it = 0; it < 4; ++it)                              \
    _Pragma("unroll") for (int ci = 0; ci < 4; ++ci) {                            \
        int row = it * 16 + srow;                                                 \
        int col = ci * 16 + scol;                                                 \
        v[it * 4 + ci] = *(const float4*)(x + (size_t)(tok0 + row) * D_DIM +      \
                                          kbase + (dbase_) + col);                \
    }

    LOAD_CHUNK(0)
    __syncthreads();   // wmS ready

    for (int s = 0; s < 8; ++s) {
        const int dbase = s * 64;
        // commit current chunk to LDS (+ fused bf16 store to xb)
#pragma unroll
        for (int it = 0; it < 4; ++it)
#pragma unroll
            for (int ci = 0; ci < 4; ++ci) {
                int row = it * 16 + srow;
                int col = ci * 16 + scol;
                *(float4*)&xs[row][col] = v[it * 4 + ci];
                if (WRITE_XB) {
                    uint2 p = pack4(v[it * 4 + ci]);
                    *(uint2*)(xb + (size_t)(tok0 + row) * D_DIM + kbase + dbase + col) = p;
                }
            }
        __syncthreads();
        if (s < 7) { LOAD_CHUNK(dbase + 64) }   // prefetch; latency hidden under dfma
        // compute: lane reads its own token row; Wm reads are uniform (broadcast)
#pragma unroll
        for (int j4 = 0; j4 < 16; ++j4) {
            float4 xv = *(const float4*)&xs[lane][j4 * 4];
#pragma unroll
            for (int g = 0; g < 8; ++g) {
                float4 wv = *(const float4*)&wmS[g][dbase + j4 * 4];
                acc[g] += (double)xv.x * (double)wv.x;
                acc[g] += (double)xv.y * (double)wv.y;
                acc[g] += (double)xv.z * (double)wv.z;
                acc[g] += (double)xv.w * (double)wv.w;
            }
        }
        __syncthreads();   // xs consumed before next overwrite
    }
#undef LOAD_CHUNK

    double* dst = part + (((size_t)t * 4 + q) * 64 + lane) * 8;
#pragma unroll
    for (int g = 0; g < 8; ++g) dst[g] = acc[g];
}

// Gate phase 2: one thread per token — sum 4 quarter-partials + bm, argmax
// (strict > == top_k lowest-index tie rule), bucket via atomic.
__global__ __launch_bounds__(256)
void gate_combine_kernel(const double* __restrict__ part, const float* __restrict__ bm,
                         int* __restrict__ cnt, int* __restrict__ bucket) {
    int tok = blockIdx.x * 256 + threadIdx.x;
    int t = tok >> 6, L = tok & 63;
    double s[8];
#pragma unroll
    for (int g = 0; g < 8; ++g) s[g] = (double)bm[g];
#pragma unroll
    for (int q = 0; q < 4; ++q) {
        const double* p = part + (((size_t)t * 4 + q) * 64 + L) * 8;
#pragma unroll
        for (int g = 0; g < 8; ++g) s[g] += p[g];
    }
    double best = s[0]; int bg = 0;
#pragma unroll
    for (int g = 1; g < 8; ++g)
        if (s[g] > best) { best = s[g]; bg = g; }
    int pos = atomicAdd(&cnt[bg], 1);
    bucket[bg * T_TOK + pos] = tok;
}

// ---------------------------------------------------------------------------
// bf16 MFMA GEMM (m97 structure) with row gather via bucket.
// 128x128 tile, BK=32, 256 threads = 4 waves, each wave 64x64 via 4x4 MFMAs.
// A_BF16/B_BF16: operand is pre-converted bf16 (async global_load_lds staging)
// vs fp32 global (register-load + in-register RNE pack + ds_write_b128).
// IS_G1: A rows gathered from x-like [*, KDIM]; B rows = W1[g*GF+nx0+..], out bf16 relu(.+b1)
// else : A rows gathered from Hb [*, GF]; B rows = W2[nx0+..] col-offset g*GF, out f32 .+b2
// ---------------------------------------------------------------------------
template <int KDIM, bool IS_G1, bool A_BF16, bool B_BF16>
__global__ __launch_bounds__(256)
void mfma_gemm(const void* __restrict__ Aop, const void* __restrict__ Bop,
               const float* __restrict__ bias,
               const int* __restrict__ cnt, const int* __restrict__ bucket,
               unsigned short* __restrict__ outH, float* __restrict__ outF) {
    const int g  = blockIdx.z;
    const int n  = cnt[g];
    const int t0 = blockIdx.y * 128;
    if (t0 >= n) return;
    const int nx0 = blockIdx.x * 128;
    const int tid  = threadIdx.x;
    const int lane = tid & 63;
    const int wv   = tid >> 6;

    __shared__ int toks[128];
    __shared__ __align__(16) unsigned short As[128 * 32];  // [row][k], 64B rows
    __shared__ __align__(16) unsigned short Bs[128 * 32];

    if (tid < 128) {
        int r = t0 + tid;
        if (r >= n) r = n - 1;       // clamp: duplicate last valid token, masked on store
        toks[tid] = bucket[g * T_TOK + r];
    }
    __syncthreads();

    const size_t bstride = IS_G1 ? (size_t)KDIM : (size_t)F_DIM;
    const size_t brow0   = IS_G1 ? (size_t)(g * GF + nx0) : (size_t)nx0;
    const size_t bcol    = IS_G1 ? 0 : (size_t)(g * GF);

    // --- bf16 async staging mapping: chunk c = tid, row c>>2, seg c&3 ---
    const int lrow = tid >> 2;
    const int lseg = tid & 3;
    const unsigned short* aP0 = nullptr; const unsigned short* aP1 = nullptr;
    const unsigned short* bP0 = nullptr; const unsigned short* bP1 = nullptr;
    char *ldsA0 = nullptr, *ldsA1 = nullptr, *ldsB0 = nullptr, *ldsB1 = nullptr;
    if (A_BF16) {
        const unsigned short* Ab = (const unsigned short*)Aop;
        aP0 = Ab + (size_t)toks[lrow] * KDIM + lseg * 8;
        aP1 = Ab + (size_t)toks[64 + lrow] * KDIM + lseg * 8;
        ldsA0 = (char*)As + tid * 16;
        ldsA1 = (char*)As + 4096 + tid * 16;
    }
    if (B_BF16) {
        const unsigned short* Bb = (const unsigned short*)Bop;
        bP0 = Bb + (brow0 + lrow) * bstride + bcol + lseg * 8;
        bP1 = Bb + (brow0 + 64 + lrow) * bstride + bcol + lseg * 8;
        ldsB0 = (char*)Bs + tid * 16;
        ldsB1 = (char*)Bs + 4096 + tid * 16;
    }

    // --- fp32 register staging mapping: row tid>>1, 16 k-elems at (tid&1)*16 ---
    const int frw = tid >> 1;
    const int fsg = (tid & 1) * 16;
    const float* aF = nullptr; const float* bF = nullptr;
    char *ldsAf = nullptr, *ldsBf = nullptr;
    if (!A_BF16) {
        aF = (const float*)Aop + (size_t)toks[frw] * KDIM + fsg;
        ldsAf = (char*)As + frw * 64 + (tid & 1) * 32;
    }
    if (!B_BF16) {
        bF = (const float*)Bop + (brow0 + frw) * bstride + bcol + fsg;
        ldsBf = (char*)Bs + frw * 64 + (tid & 1) * 32;
    }

    f32x4 acc[4][4];
#pragma unroll
    for (int mi = 0; mi < 4; ++mi)
#pragma unroll
        for (int ni = 0; ni < 4; ++ni)
            acc[mi][ni] = (f32x4){0.f, 0.f, 0.f, 0.f};

    const int wr   = (wv >> 1) * 64;   // wave row offset in 128-tile
    const int wc   = (wv & 1) * 64;    // wave col offset
    const int frow = lane & 15;
    const int kh   = lane >> 4;

    for (int k0 = 0; k0 < KDIM; k0 += 32) {
        __syncthreads();               // prev iter's LDS reads done
        if (A_BF16) { async_load16(aP0 + k0, ldsA0); async_load16(aP1 + k0, ldsA1); }
        if (B_BF16) { async_load16(bP0 + k0, ldsB0); async_load16(bP1 + k0, ldsB1); }
        if (!A_BF16) {
            float4 v0 = *(const float4*)(aF + k0);
            float4 v1 = *(const float4*)(aF + k0 + 4);
            float4 v2 = *(const float4*)(aF + k0 + 8);
            float4 v3 = *(const float4*)(aF + k0 + 12);
            uint2 p0 = pack4(v0), p1 = pack4(v1), p2 = pack4(v2), p3 = pack4(v3);
            uint4 w0; w0.x = p0.x; w0.y = p0.y; w0.z = p1.x; w0.w = p1.y;
            uint4 w1; w1.x = p2.x; w1.y = p2.y; w1.z = p3.x; w1.w = p3.y;
            *(uint4*)ldsAf = w0; *(uint4*)(ldsAf + 16) = w1;
        }
        if (!B_BF16) {
            float4 v0 = *(const float4*)(bF + k0);
            float4 v1 = *(const float4*)(bF + k0 + 4);
            float4 v2 = *(const float4*)(bF + k0 + 8);
            float4 v3 = *(const float4*)(bF + k0 + 12);
            uint2 p0 = pack4(v0), p1 = pack4(v1), p2 = pack4(v2), p3 = pack4(v3);
            uint4 w0; w0.x = p0.x; w0.y = p0.y; w0.z = p1.x; w0.w = p1.y;
            uint4 w1; w1.x = p2.x; w1.y = p2.y; w1.z = p3.x; w1.w = p3.y;
            *(uint4*)ldsBf = w0; *(uint4*)(ldsBf + 16) = w1;
        }
        __syncthreads();               // staging visible (vmcnt + lgkmcnt drained)
        bf16x8 af[4], bfr[4];
#pragma unroll
        for (int mi = 0; mi < 4; ++mi)
            af[mi] = *(const bf16x8*)((const char*)As + (size_t)(wr + mi * 16 + frow) * 64 + kh * 16);
#pragma unroll
        for (int ni = 0; ni < 4; ++ni)
            bfr[ni] = *(const bf16x8*)((const char*)Bs + (size_t)(wc + ni * 16 + frow) * 64 + kh * 16);
#pragma unroll
        for (int mi = 0; mi < 4; ++mi)
#pragma unroll
            for (int ni = 0; ni < 4; ++ni)
                acc[mi][ni] = __builtin_amdgcn_mfma_f32_16x16x32_bf16(
                    af[mi], bfr[ni], acc[mi][ni], 0, 0, 0);
    }

    // epilogue: C elem (row = mi*16 + kh*4 + v, col = ni*16 + frow)  [m89 mapping]
    const float* bptr = bias + (IS_G1 ? (g * GF + nx0) : nx0);
    float bv[4];
#pragma unroll
    for (int ni = 0; ni < 4; ++ni) bv[ni] = bptr[wc + ni * 16 + frow];

#pragma unroll
    for (int mi = 0; mi < 4; ++mi) {
#pragma unroll
        for (int v = 0; v < 4; ++v) {
            int r = wr + mi * 16 + kh * 4 + v;
            if (t0 + r < n) {
                int tok = toks[r];
                if (IS_G1) {
                    unsigned short* dst = outH + (size_t)tok * GF + nx0 + wc + frow;
#pragma unroll
                    for (int ni = 0; ni < 4; ++ni) {
                        float o = fmaxf(acc[mi][ni][v] + bv[ni], 0.f);
                        dst[ni * 16] = f2bf(o);
                    }
                } else {
                    float* dst = outF + (size_t)tok * D_DIM + nx0 + wc + frow;
#pragma unroll
                    for (int ni = 0; ni < 4; ++ni)
                        dst[ni * 16] = acc[mi][ni][v] + bv[ni];
                }
            }
        }
    }
}

extern "C" void kernel_launch(void* const* d_in, const int* in_sizes, int n_in,
                              void* d_out, int out_size, void* d_ws, size_t ws_size,
                              hipStream_t stream) {
    const float* x  = (const float*)d_in[0];
    const float* W1 = (const float*)d_in[1];
    const float* b1 = (const float*)d_in[2];
    const float* Wm = (const float*)d_in[3];
    const float* bm = (const float*)d_in[4];
    const float* W2 = (const float*)d_in[5];
    const float* b2 = (const float*)d_in[6];
    float* out = (float*)d_out;

    int* cnt    = (int*)d_ws;
    int* bucket = (int*)((char*)d_ws + 1024);
    double* part = (double*)((char*)d_ws + (1 << 19));   // 2 MiB, aliases Hb (safe: consumed first)
    unsigned short* Hb  = (unsigned short*)((char*)d_ws + (1 << 19));
    unsigned short* xb  = Hb  + (size_t)T_TOK * GF;
    unsigned short* W1b = xb  + (size_t)T_TOK * D_DIM;
    unsigned short* W2b = W1b + (size_t)F_DIM * D_DIM;

    // FAST 112.5 MiB | MID 48.5 MiB | SAFE 16.5 MiB
    const bool fast = ws_size >= 117964800ull;
    const bool mid  = ws_size >= 50855936ull;
    const int NCVT = T_TOK * D_DIM;  // == F*D == D*F == 16777216

    zero_cnt_kernel<<<1, 64, 0, stream>>>(cnt);
    if (fast || mid)
        gate_partial_kernel<true><<<dim3(4, 128), 64, 0, stream>>>(x, Wm, xb, part);
    else
        gate_partial_kernel<false><<<dim3(4, 128), 64, 0, stream>>>(x, Wm, nullptr, part);
    gate_combine_kernel<<<T_TOK / 256, 256, 0, stream>>>(part, bm, cnt, bucket);

    if (fast) {
        convert_kernel<<<NCVT / (256 * 8), 256, 0, stream>>>(W1, W1b, NCVT);
        convert_kernel<<<NCVT / (256 * 8), 256, 0, stream>>>(W2, W2b, NCVT);
        mfma_gemm<D_DIM, true, true, true><<<dim3(GF / 128, T_TOK / 128, G_NUM), 256, 0, stream>>>(
            xb, W1b, b1, cnt, bucket, Hb, nullptr);
        mfma_gemm<GF, false, true, true><<<dim3(D_DIM / 128, T_TOK / 128, G_NUM), 256, 0, stream>>>(
            Hb, W2b, b2, cnt, bucket, nullptr, out);
    } else if (mid) {
        mfma_gemm<D_DIM, true, true, false><<<dim3(GF / 128, T_TOK / 128, G_NUM), 256, 0, stream>>>(
            xb, W1, b1, cnt, bucket, Hb, nullptr);
        mfma_gemm<GF, false, true, false><<<dim3(D_DIM / 128, T_TOK / 128, G_NUM), 256, 0, stream>>>(
            Hb, W2, b2, cnt, bucket, nullptr, out);
    } else {
        mfma_gemm<D_DIM, true, false, false><<<dim3(GF / 128, T_TOK / 128, G_NUM), 256, 0, stream>>>(
            x, W1, b1, cnt, bucket, Hb, nullptr);
        mfma_gemm<GF, false, true, false><<<dim3(D_DIM / 128, T_TOK / 128, G_NUM), 256, 0, stream>>>(
            Hb, W2, b2, cnt, bucket, nullptr, out);
    }
}